// Round 1
// baseline (61.276 us; speedup 1.0000x reference)
//
#include <hip/hip_runtime.h>
#include <hip/hip_bf16.h>

// SH degree-4 encoder: [N,3] f32 normalized dirs -> [N,16] f32.
// Memory-bound (76 B/point, no reuse). LDS-transpose the 16 outputs per
// point so global stores are fully coalesced.

#define C0    0.28209479177387814f
#define C1    0.48860251190291987f
#define C2_0  1.0925484305920792f
#define C2_2  0.94617469575755997f
#define C2_2b 0.31539156525251999f
#define C2_4  0.54627421529603959f
#define C3_0  0.59004358992664352f
#define C3_1  2.8906114426405538f
#define C3_2  0.45704579946446572f
#define C3_3  0.3731763325901154f
#define C3_5  1.4453057213202769f

#define BLK 256
#define NPAD 17  // row stride in words: odd -> conflict-free LDS writes

__global__ __launch_bounds__(BLK) void sh_encode_kernel(
    const float* __restrict__ din, float* __restrict__ dout, int N) {
    __shared__ float s[BLK * NPAD];  // 17408 B -> 8 blocks/CU, full 32 waves

    const int tid  = threadIdx.x;
    const int base = blockIdx.x * BLK;
    const int i    = base + tid;

    float x = 0.f, y = 0.f, z = 0.f;
    if (i < N) {
        const float* p = din + (size_t)3 * i;
        x = p[0]; y = p[1]; z = p[2];
    }

    const float x2 = x * x, y2 = y * y, z2 = z * z;
    const float xy = x * y, yz = y * z, xz = x * z;

    float t[16];
    t[0]  = C0;
    t[1]  = -C1 * y;
    t[2]  =  C1 * z;
    t[3]  = -C1 * x;
    t[4]  =  C2_0 * xy;
    t[5]  = -C2_0 * yz;
    t[6]  =  C2_2 * z2 - C2_2b;
    t[7]  = -C2_0 * xz;
    t[8]  =  C2_4 * (x2 - y2);
    t[9]  =  C3_0 * y * (-3.0f * x2 + y2);
    t[10] =  C3_1 * xy * z;
    t[11] =  C3_2 * y * (1.0f - 5.0f * z2);
    t[12] =  C3_3 * z * (5.0f * z2 - 3.0f);
    t[13] =  C3_2 * x * (1.0f - 5.0f * z2);
    t[14] =  C3_5 * z * (x2 - y2);
    t[15] =  C3_0 * x * (-x2 + 3.0f * y2);

    // LDS stage: lane tid writes its 16 results at row stride 17 (odd ->
    // all 64 lanes hit distinct banks per write instruction).
    #pragma unroll
    for (int k = 0; k < 16; ++k) s[tid * NPAD + k] = t[k];

    __syncthreads();

    // Coalesced drain: iteration `it` writes elements [it*256, it*256+256)
    // of this block's contiguous 4096-float output span. Each wave store
    // instruction covers a contiguous 256 B segment.
    float* outb = dout + (size_t)base * 16;
    #pragma unroll
    for (int it = 0; it < 16; ++it) {
        const int e = it * BLK + tid;          // 0..4095
        const int p = e >> 4, k = e & 15;
        if (base + p < N) outb[e] = s[p * NPAD + k];
    }
}

extern "C" void kernel_launch(void* const* d_in, const int* in_sizes, int n_in,
                              void* d_out, int out_size, void* d_ws, size_t ws_size,
                              hipStream_t stream) {
    const float* din = (const float*)d_in[0];
    float* dout      = (float*)d_out;
    const int N      = in_sizes[0] / 3;
    const int blocks = (N + BLK - 1) / BLK;
    sh_encode_kernel<<<blocks, BLK, 0, stream>>>(din, dout, N);
}

// Round 2
// 57.841 us; speedup vs baseline: 1.0594x; 1.0594x over previous
//
#include <hip/hip_runtime.h>
#include <hip/hip_bf16.h>

// SH degree-4 encoder: [N,3] f32 normalized dirs -> [N,16] f32.
// Memory-bound (76 B/point, no reuse). XOR-swizzled float4 LDS transpose
// so global stores are coalesced 16 B/lane dwordx4.

#define C0    0.28209479177387814f
#define C1    0.48860251190291987f
#define C2_0  1.0925484305920792f
#define C2_2  0.94617469575755997f
#define C2_2b 0.31539156525251999f
#define C2_4  0.54627421529603959f
#define C3_0  0.59004358992664352f
#define C3_1  2.8906114426405538f
#define C3_2  0.45704579946446572f
#define C3_3  0.3731763325901154f
#define C3_5  1.4453057213202769f

#define BLK 256

__global__ __launch_bounds__(BLK) void sh_encode_kernel(
    const float* __restrict__ din, float* __restrict__ dout, int N) {
    // Point p's logical quad q lives at s4[p*4 + (q ^ ((p>>1)&3))].
    // XOR swizzle makes both ds_write_b128 and ds_read_b128 phases tile
    // all 32 banks (even lanes -> banks {0,4,8,12}, odd -> {16,20,24,28}).
    __shared__ float4 s4[BLK * 4];  // 16 KiB -> 8 blocks/CU

    const int tid  = threadIdx.x;
    const int base = blockIdx.x * BLK;
    const int i    = base + tid;

    float x = 0.f, y = 0.f, z = 0.f;
    if (i < N) {
        const float* p = din + (size_t)3 * i;
        x = p[0]; y = p[1]; z = p[2];
    }

    const float x2 = x * x, y2 = y * y, z2 = z * z;
    const float xy = x * y, yz = y * z, xz = x * z;

    float t[16];
    t[0]  = C0;
    t[1]  = -C1 * y;
    t[2]  =  C1 * z;
    t[3]  = -C1 * x;
    t[4]  =  C2_0 * xy;
    t[5]  = -C2_0 * yz;
    t[6]  =  C2_2 * z2 - C2_2b;
    t[7]  = -C2_0 * xz;
    t[8]  =  C2_4 * (x2 - y2);
    t[9]  =  C3_0 * y * (-3.0f * x2 + y2);
    t[10] =  C3_1 * xy * z;
    t[11] =  C3_2 * y * (1.0f - 5.0f * z2);
    t[12] =  C3_3 * z * (5.0f * z2 - 3.0f);
    t[13] =  C3_2 * x * (1.0f - 5.0f * z2);
    t[14] =  C3_5 * z * (x2 - y2);
    t[15] =  C3_0 * x * (-x2 + 3.0f * y2);

    const int sw = (tid >> 1) & 3;
    #pragma unroll
    for (int g = 0; g < 4; ++g) {
        s4[tid * 4 + (g ^ sw)] =
            make_float4(t[4 * g], t[4 * g + 1], t[4 * g + 2], t[4 * g + 3]);
    }

    __syncthreads();

    // Drain: iteration `it` writes float4s [it*256, it*256+256) of this
    // block's contiguous 1024-float4 output span. Each wave store is a
    // contiguous 1 KiB global_store_dwordx4 segment.
    float4* outb4 = (float4*)(dout + (size_t)base * 16);
    #pragma unroll
    for (int it = 0; it < 4; ++it) {
        const int e4 = it * BLK + tid;      // 0..1023
        const int p  = e4 >> 2;             // point within block
        const int q  = e4 & 3;              // logical quad
        if (base + p < N)
            outb4[e4] = s4[p * 4 + (q ^ ((p >> 1) & 3))];
    }
}

extern "C" void kernel_launch(void* const* d_in, const int* in_sizes, int n_in,
                              void* d_out, int out_size, void* d_ws, size_t ws_size,
                              hipStream_t stream) {
    const float* din = (const float*)d_in[0];
    float* dout      = (float*)d_out;
    const int N      = in_sizes[0] / 3;
    const int blocks = (N + BLK - 1) / BLK;
    sh_encode_kernel<<<blocks, BLK, 0, stream>>>(din, dout, N);
}

// Round 3
// 50.200 us; speedup vs baseline: 1.2206x; 1.1522x over previous
//
#include <hip/hip_runtime.h>
#include <hip/hip_bf16.h>

// SH degree-4 encoder: [N,3] f32 normalized dirs -> [N,16] f32.
// Memory-bound (76 B/point). Per-WAVE LDS transpose (no s_barrier):
// each wave stages its 64 points' outputs in a private 4 KiB LDS region
// (XOR-swizzled, conflict-free), then drains its own contiguous 4 KiB
// output span with nontemporal global_store_dwordx4.

#define C0    0.28209479177387814f
#define C1    0.48860251190291987f
#define C2_0  1.0925484305920792f
#define C2_2  0.94617469575755997f
#define C2_2b 0.31539156525251999f
#define C2_4  0.54627421529603959f
#define C3_0  0.59004358992664352f
#define C3_1  2.8906114426405538f
#define C3_2  0.45704579946446572f
#define C3_3  0.3731763325901154f
#define C3_5  1.4453057213202769f

#define BLK 256

typedef float f4 __attribute__((ext_vector_type(4)));

__global__ __launch_bounds__(BLK) void sh_encode_kernel(
    const float* __restrict__ din, float* __restrict__ dout, int N) {
    // Wave w owns s4[w*256 .. w*256+256) (4 KiB). Point-in-wave p's logical
    // quad q lives at [p*4 + (q ^ ((p>>1)&3))] — XOR swizzle tiles all 32
    // banks for both ds_write_b128 and ds_read_b128 (0 conflicts, R1/R2).
    __shared__ f4 s4[BLK * 4];  // 16 KiB -> 8 blocks/CU

    const int tid  = threadIdx.x;
    const int lane = tid & 63;
    const int wave = tid >> 6;
    const int base = blockIdx.x * BLK;
    const int i    = base + tid;
    const bool full = (base + BLK) <= N;

    float x = 0.f, y = 0.f, z = 0.f;
    if (full || i < N) {
        const float* p = din + (size_t)3 * i;
        x = p[0]; y = p[1]; z = p[2];
    }

    const float x2 = x * x, y2 = y * y, z2 = z * z;
    const float xy = x * y, yz = y * z, xz = x * z;

    float t[16];
    t[0]  = C0;
    t[1]  = -C1 * y;
    t[2]  =  C1 * z;
    t[3]  = -C1 * x;
    t[4]  =  C2_0 * xy;
    t[5]  = -C2_0 * yz;
    t[6]  =  C2_2 * z2 - C2_2b;
    t[7]  = -C2_0 * xz;
    t[8]  =  C2_4 * (x2 - y2);
    t[9]  =  C3_0 * y * (-3.0f * x2 + y2);
    t[10] =  C3_1 * xy * z;
    t[11] =  C3_2 * y * (1.0f - 5.0f * z2);
    t[12] =  C3_3 * z * (5.0f * z2 - 3.0f);
    t[13] =  C3_2 * x * (1.0f - 5.0f * z2);
    t[14] =  C3_5 * z * (x2 - y2);
    t[15] =  C3_0 * x * (-x2 + 3.0f * y2);

    f4* ws = s4 + (wave << 8);          // this wave's private region
    const int sw = (lane >> 1) & 3;
    #pragma unroll
    for (int g = 0; g < 4; ++g) {
        f4 v = {t[4 * g], t[4 * g + 1], t[4 * g + 2], t[4 * g + 3]};
        ws[(lane << 2) + (g ^ sw)] = v;
    }

    // Intra-wave producer->consumer: wait for this wave's ds_writes only.
    // "memory" clobber pins ds ops on both sides of the waitcnt.
    asm volatile("s_waitcnt lgkmcnt(0)" ::: "memory");

    // Drain: this wave's 64 points -> contiguous 4 KiB of output.
    const int wbase = base + (wave << 6);
    f4* outw = (f4*)dout + ((size_t)wbase << 2);
    if (full) {
        #pragma unroll
        for (int it = 0; it < 4; ++it) {
            const int e4 = (it << 6) + lane;    // 0..255 within wave span
            const int p  = e4 >> 2, q = e4 & 3;
            __builtin_nontemporal_store(ws[(p << 2) + (q ^ ((p >> 1) & 3))],
                                        &outw[e4]);
        }
    } else {
        for (int it = 0; it < 4; ++it) {
            const int e4 = (it << 6) + lane;
            const int p  = e4 >> 2, q = e4 & 3;
            if (wbase + p < N)
                __builtin_nontemporal_store(ws[(p << 2) + (q ^ ((p >> 1) & 3))],
                                            &outw[e4]);
        }
    }
}

extern "C" void kernel_launch(void* const* d_in, const int* in_sizes, int n_in,
                              void* d_out, int out_size, void* d_ws, size_t ws_size,
                              hipStream_t stream) {
    const float* din = (const float*)d_in[0];
    float* dout      = (float*)d_out;
    const int N      = in_sizes[0] / 3;
    const int blocks = (N + BLK - 1) / BLK;
    sh_encode_kernel<<<blocks, BLK, 0, stream>>>(din, dout, N);
}